// Round 1
// baseline (1304.263 us; speedup 1.0000x reference)
//
#include <hip/hip_runtime.h>
#include <hip/hip_bf16.h>

#define E_ 8
#define K_ 2
#define D_ 1024
#define F_ 4096
#define FS_ 2048
#define N_ 2048
#define ROWS_CAP 4352

typedef __bf16 bf16x8 __attribute__((ext_vector_type(8)));
typedef float f32x4 __attribute__((ext_vector_type(4)));

static __device__ __forceinline__ unsigned short f2bf(float f) {
  union { float f; unsigned int u; } v; v.f = f;
  unsigned int u = v.u;
  return (unsigned short)((u + 0x7FFF + ((u >> 16) & 1)) >> 16);  // RNE
}

__global__ void init_k(int* counts) {
  if (threadIdx.x < E_) counts[threadIdx.x] = 0;
}

// One wave per token: logits, softmax, top-2, counts; also casts x row to bf16.
__global__ void router_k(const float* __restrict__ x, const float* __restrict__ gw,
                         unsigned short* __restrict__ xbf, float* __restrict__ topw,
                         int* __restrict__ topi, int* __restrict__ counts) {
  int wave = threadIdx.x >> 6, lane = threadIdx.x & 63;
  int n = blockIdx.x * 4 + wave;
  const float* xr = x + (size_t)n * D_;
  float v[16];
#pragma unroll
  for (int j = 0; j < 16; ++j) v[j] = xr[lane + 64 * j];
#pragma unroll
  for (int j = 0; j < 16; ++j) xbf[(size_t)n * D_ + lane + 64 * j] = f2bf(v[j]);
  float logit[E_];
  for (int e = 0; e < E_; ++e) {
    const float* g = gw + e * D_;
    float acc = 0.f;
#pragma unroll
    for (int j = 0; j < 16; ++j) acc += v[j] * g[lane + 64 * j];
#pragma unroll
    for (int off = 32; off > 0; off >>= 1) acc += __shfl_down(acc, off, 64);
    logit[e] = __shfl(acc, 0, 64);
  }
  if (lane == 0) {
    float m = logit[0];
    for (int e = 1; e < E_; ++e) m = fmaxf(m, logit[e]);
    float p[E_], s = 0.f;
    for (int e = 0; e < E_; ++e) { p[e] = expf(logit[e] - m); s += p[e]; }
    float inv = 1.f / s;
    for (int e = 0; e < E_; ++e) p[e] *= inv;
    int i0 = 0;
    for (int e = 1; e < E_; ++e) if (p[e] > p[i0]) i0 = e;
    int i1 = (i0 == 0) ? 1 : 0;
    for (int e = 0; e < E_; ++e) if (e != i0 && p[e] > p[i1]) i1 = e;
    topi[n * 2] = i0; topi[n * 2 + 1] = i1;
    topw[n * 2] = p[i0]; topw[n * 2 + 1] = p[i1];
    atomicAdd(&counts[i0], 1);
    atomicAdd(&counts[i1], 1);
  }
}

__global__ void scan_k(const int* __restrict__ counts, int* __restrict__ offs,
                       int* __restrict__ cursor) {
  if (threadIdx.x == 0) {
    int o = 0;
    for (int e = 0; e < E_; ++e) { offs[e] = o; o += counts[e]; cursor[e] = 0; }
    offs[E_] = o;
  }
}

__global__ void fill_k(const int* __restrict__ topi, const int* __restrict__ offs,
                       int* __restrict__ cursor, int* __restrict__ rowlist,
                       int* __restrict__ slot_of) {
  int n = blockIdx.x * blockDim.x + threadIdx.x;
  if (n >= N_) return;
  for (int k = 0; k < K_; ++k) {
    int e = topi[n * 2 + k];
    int pos = offs[e] + atomicAdd(&cursor[e], 1);
    rowlist[pos] = n;
    slot_of[n * 2 + k] = pos;
  }
}

// Fused gate+up GEMM: [Me,Kdim](bf16, gathered rows) x [Kdim,Ncols](fp32) for two
// weight matrices; epilogue writes silu(g)*u as bf16 to Out (row = slotbase+m).
__launch_bounds__(256, 2)
__global__ void gemm1_k(const unsigned short* __restrict__ Abase,
                        const int* __restrict__ rowlist,
                        const int* __restrict__ offs, int Mfixed,
                        const float* __restrict__ Bg_base,
                        const float* __restrict__ Bu_base,
                        int Ncols, int Kdim,
                        unsigned short* __restrict__ Out) {
  int e = blockIdx.z;
  int Me, slotbase;
  if (offs) { slotbase = offs[e]; Me = offs[e + 1] - slotbase; }
  else      { slotbase = 0;       Me = Mfixed; }
  int mbase = blockIdx.x * 128;
  if (mbase >= Me) return;
  int nbase = blockIdx.y * 128;
  const float* Bg = Bg_base + (size_t)e * Kdim * Ncols;
  const float* Bu = Bu_base + (size_t)e * Kdim * Ncols;

  __shared__ unsigned short As[128][40];
  __shared__ unsigned short Bgs[128][40];
  __shared__ unsigned short Bus[128][40];

  int t = threadIdx.x;
  int lane = t & 63, wave = t >> 6;
  int wm = wave >> 1, wn = wave & 1;

  f32x4 accg[4][4], accu[4][4];
#pragma unroll
  for (int i = 0; i < 4; ++i)
#pragma unroll
    for (int j = 0; j < 4; ++j) {
      accg[i][j] = f32x4{0.f, 0.f, 0.f, 0.f};
      accu[i][j] = f32x4{0.f, 0.f, 0.f, 0.f};
    }

  // A staging: thread -> (row = t>>1, k-half = t&1), 16 bf16 per thread per iter
  int ar = t >> 1, akh = t & 1;
  int arow = mbase + ar;
  int asrc = 0;
  if (arow < Me) asrc = rowlist ? rowlist[slotbase + arow] : arow;
  const unsigned short* aptr = Abase + (size_t)asrc * Kdim + akh * 16;
  // B staging: thread -> (col f = t&127, k-half = t>>7), 16 strided fp32 per matrix
  int bfc = t & 127, bkh = t >> 7;
  const float* bgp = Bg + (size_t)(bkh * 16) * Ncols + nbase + bfc;
  const float* bup = Bu + (size_t)(bkh * 16) * Ncols + nbase + bfc;

  int nk = Kdim >> 5;
  for (int kt = 0; kt < nk; ++kt) {
    uint4 a0 = *(const uint4*)(aptr + kt * 32);
    uint4 a1 = *(const uint4*)(aptr + kt * 32 + 8);
    *(uint4*)&As[ar][akh * 16] = a0;
    *(uint4*)&As[ar][akh * 16 + 8] = a1;
    {
      const float* p0 = bgp + (size_t)kt * 32 * Ncols;
      float bv[16];
#pragma unroll
      for (int i = 0; i < 16; ++i) bv[i] = p0[(size_t)i * Ncols];
      unsigned short h[16];
#pragma unroll
      for (int i = 0; i < 16; ++i) h[i] = f2bf(bv[i]);
      *(uint4*)&Bgs[bfc][bkh * 16] = *(uint4*)&h[0];
      *(uint4*)&Bgs[bfc][bkh * 16 + 8] = *(uint4*)&h[8];
    }
    {
      const float* p1 = bup + (size_t)kt * 32 * Ncols;
      float bv[16];
#pragma unroll
      for (int i = 0; i < 16; ++i) bv[i] = p1[(size_t)i * Ncols];
      unsigned short h[16];
#pragma unroll
      for (int i = 0; i < 16; ++i) h[i] = f2bf(bv[i]);
      *(uint4*)&Bus[bfc][bkh * 16] = *(uint4*)&h[0];
      *(uint4*)&Bus[bfc][bkh * 16 + 8] = *(uint4*)&h[8];
    }
    __syncthreads();
    bf16x8 afr[4];
#pragma unroll
    for (int i = 0; i < 4; ++i)
      afr[i] = *(const bf16x8*)&As[wm * 64 + i * 16 + (lane & 15)][(lane >> 4) * 8];
#pragma unroll
    for (int j = 0; j < 4; ++j) {
      bf16x8 bg = *(const bf16x8*)&Bgs[wn * 64 + j * 16 + (lane & 15)][(lane >> 4) * 8];
      bf16x8 bu = *(const bf16x8*)&Bus[wn * 64 + j * 16 + (lane & 15)][(lane >> 4) * 8];
#pragma unroll
      for (int i = 0; i < 4; ++i) {
        accg[i][j] = __builtin_amdgcn_mfma_f32_16x16x32_bf16(afr[i], bg, accg[i][j], 0, 0, 0);
        accu[i][j] = __builtin_amdgcn_mfma_f32_16x16x32_bf16(afr[i], bu, accu[i][j], 0, 0, 0);
      }
    }
    __syncthreads();
  }
  // epilogue: silu(g)*u -> bf16
  int r0 = (lane >> 4) * 4, cn = lane & 15;
#pragma unroll
  for (int i = 0; i < 4; ++i) {
#pragma unroll
    for (int rr = 0; rr < 4; ++rr) {
      int grow = mbase + wm * 64 + i * 16 + r0 + rr;
      if (grow < Me) {
        size_t rbase = (size_t)(slotbase + grow) * Ncols + nbase;
#pragma unroll
        for (int j = 0; j < 4; ++j) {
          float g = accg[i][j][rr], u = accu[i][j][rr];
          float a = (g / (1.f + __expf(-g))) * u;
          Out[rbase + wn * 64 + j * 16 + cn] = f2bf(a);
        }
      }
    }
  }
}

// Down-projection GEMM: [Me,Kdim](bf16, consecutive rows at slotbase) x [Kdim,Ncols](fp32)
__launch_bounds__(256, 2)
__global__ void gemm2_k(const unsigned short* __restrict__ Abase,
                        const int* __restrict__ offs, int Mfixed,
                        const float* __restrict__ B_base,
                        int Ncols, int Kdim,
                        float* __restrict__ Out) {
  int e = blockIdx.z;
  int Me, slotbase;
  if (offs) { slotbase = offs[e]; Me = offs[e + 1] - slotbase; }
  else      { slotbase = 0;       Me = Mfixed; }
  int mbase = blockIdx.x * 128;
  if (mbase >= Me) return;
  int nbase = blockIdx.y * 128;
  const float* B = B_base + (size_t)e * Kdim * Ncols;

  __shared__ unsigned short As[128][40];
  __shared__ unsigned short Bs[128][40];

  int t = threadIdx.x;
  int lane = t & 63, wave = t >> 6;
  int wm = wave >> 1, wn = wave & 1;

  f32x4 acc[4][4];
#pragma unroll
  for (int i = 0; i < 4; ++i)
#pragma unroll
    for (int j = 0; j < 4; ++j) acc[i][j] = f32x4{0.f, 0.f, 0.f, 0.f};

  int ar = t >> 1, akh = t & 1;
  int arow = slotbase + ((mbase + ar < Me) ? (mbase + ar) : 0);
  const unsigned short* aptr = Abase + (size_t)arow * Kdim + akh * 16;
  int bfc = t & 127, bkh = t >> 7;
  const float* bp = B + (size_t)(bkh * 16) * Ncols + nbase + bfc;

  int nk = Kdim >> 5;
  for (int kt = 0; kt < nk; ++kt) {
    uint4 a0 = *(const uint4*)(aptr + kt * 32);
    uint4 a1 = *(const uint4*)(aptr + kt * 32 + 8);
    *(uint4*)&As[ar][akh * 16] = a0;
    *(uint4*)&As[ar][akh * 16 + 8] = a1;
    {
      const float* p0 = bp + (size_t)kt * 32 * Ncols;
      float bv[16];
#pragma unroll
      for (int i = 0; i < 16; ++i) bv[i] = p0[(size_t)i * Ncols];
      unsigned short h[16];
#pragma unroll
      for (int i = 0; i < 16; ++i) h[i] = f2bf(bv[i]);
      *(uint4*)&Bs[bfc][bkh * 16] = *(uint4*)&h[0];
      *(uint4*)&Bs[bfc][bkh * 16 + 8] = *(uint4*)&h[8];
    }
    __syncthreads();
    bf16x8 afr[4];
#pragma unroll
    for (int i = 0; i < 4; ++i)
      afr[i] = *(const bf16x8*)&As[wm * 64 + i * 16 + (lane & 15)][(lane >> 4) * 8];
#pragma unroll
    for (int j = 0; j < 4; ++j) {
      bf16x8 bb = *(const bf16x8*)&Bs[wn * 64 + j * 16 + (lane & 15)][(lane >> 4) * 8];
#pragma unroll
      for (int i = 0; i < 4; ++i)
        acc[i][j] = __builtin_amdgcn_mfma_f32_16x16x32_bf16(afr[i], bb, acc[i][j], 0, 0, 0);
    }
    __syncthreads();
  }
  int r0 = (lane >> 4) * 4, cn = lane & 15;
#pragma unroll
  for (int i = 0; i < 4; ++i) {
#pragma unroll
    for (int rr = 0; rr < 4; ++rr) {
      int grow = mbase + wm * 64 + i * 16 + r0 + rr;
      if (grow < Me) {
        size_t rbase = (size_t)(slotbase + grow) * Ncols + nbase;
#pragma unroll
        for (int j = 0; j < 4; ++j)
          Out[rbase + wn * 64 + j * 16 + cn] = acc[i][j][rr];
      }
    }
  }
}

__global__ void combine_k(const float* __restrict__ eo, const float* __restrict__ sh,
                          const float* __restrict__ topw, const int* __restrict__ slot_of,
                          float* __restrict__ out) {
  int idx = blockIdx.x * blockDim.x + threadIdx.x;  // one float4 per thread
  int n = idx >> 8;   // D_/4 = 256
  int d4 = idx & 255;
  float w0 = topw[n * 2], w1 = topw[n * 2 + 1];
  int s0 = slot_of[n * 2], s1 = slot_of[n * 2 + 1];
  float4 a = ((const float4*)(eo + (size_t)s0 * D_))[d4];
  float4 b = ((const float4*)(eo + (size_t)s1 * D_))[d4];
  float4 c = ((const float4*)(sh + (size_t)n * D_))[d4];
  float4 r;
  r.x = w0 * a.x + w1 * b.x + c.x;
  r.y = w0 * a.y + w1 * b.y + c.y;
  r.z = w0 * a.z + w1 * b.z + c.z;
  r.w = w0 * a.w + w1 * b.w + c.w;
  ((float4*)out)[idx] = r;
}

extern "C" void kernel_launch(void* const* d_in, const int* in_sizes, int n_in,
                              void* d_out, int out_size, void* d_ws, size_t ws_size,
                              hipStream_t stream) {
  const float* x  = (const float*)d_in[0];
  const float* gw = (const float*)d_in[1];
  const float* gk = (const float*)d_in[2];
  const float* uk = (const float*)d_in[3];
  const float* dk = (const float*)d_in[4];
  const float* sg = (const float*)d_in[5];
  const float* su = (const float*)d_in[6];
  const float* sd = (const float*)d_in[7];
  float* out = (float*)d_out;

  char* w = (char*)d_ws;
  size_t o = 0;
  auto take = [&](size_t bytes) -> void* {
    void* p = w + o;
    o += (bytes + 255) & ~(size_t)255;
    return p;
  };
  unsigned short* xbf    = (unsigned short*)take((size_t)N_ * D_ * 2);
  unsigned short* act    = (unsigned short*)take((size_t)ROWS_CAP * F_ * 2);
  unsigned short* act_sh = (unsigned short*)take((size_t)N_ * FS_ * 2);
  float* eo     = (float*)take((size_t)ROWS_CAP * D_ * 4);
  float* sh_out = (float*)take((size_t)N_ * D_ * 4);
  float* topw   = (float*)take((size_t)N_ * 2 * 4);
  int* topi     = (int*)take((size_t)N_ * 2 * 4);
  int* slot_of  = (int*)take((size_t)N_ * 2 * 4);
  int* rowlist  = (int*)take((size_t)ROWS_CAP * 4);
  int* counts   = (int*)take(E_ * 4);
  int* offs     = (int*)take((E_ + 1) * 4);
  int* cursor   = (int*)take(E_ * 4);

  hipLaunchKernelGGL(init_k, dim3(1), dim3(64), 0, stream, counts);
  hipLaunchKernelGGL(router_k, dim3(N_ / 4), dim3(256), 0, stream,
                     x, gw, xbf, topw, topi, counts);
  hipLaunchKernelGGL(scan_k, dim3(1), dim3(32), 0, stream, counts, offs, cursor);
  hipLaunchKernelGGL(fill_k, dim3(N_ / 256), dim3(256), 0, stream,
                     topi, offs, cursor, rowlist, slot_of);
  // routed gate/up: grid x=mtiles(16 worst case), y=F tiles(32), z=E
  hipLaunchKernelGGL(gemm1_k, dim3(16, F_ / 128, E_), dim3(256), 0, stream,
                     xbf, rowlist, offs, 0, gk, uk, F_, D_, act);
  // shared gate/up: M=N_ tokens, Ncols=FS
  hipLaunchKernelGGL(gemm1_k, dim3(16, FS_ / 128, 1), dim3(256), 0, stream,
                     xbf, (const int*)nullptr, (const int*)nullptr, N_, sg, su, FS_, D_, act_sh);
  // routed down
  hipLaunchKernelGGL(gemm2_k, dim3(16, D_ / 128, E_), dim3(256), 0, stream,
                     act, offs, 0, dk, D_, F_, eo);
  // shared down
  hipLaunchKernelGGL(gemm2_k, dim3(16, D_ / 128, 1), dim3(256), 0, stream,
                     act_sh, (const int*)nullptr, N_, sd, D_, FS_, sh_out);
  hipLaunchKernelGGL(combine_k, dim3((N_ * D_ / 4) / 256), dim3(256), 0, stream,
                     eo, sh_out, topw, slot_of, out);
}

// Round 2
// 779.832 us; speedup vs baseline: 1.6725x; 1.6725x over previous
//
#include <hip/hip_runtime.h>
#include <hip/hip_bf16.h>

#define E_ 8
#define K_ 2
#define D_ 1024
#define F_ 4096
#define FS_ 2048
#define N_ 2048
#define ROWS_CAP 4352
#define TILE_CAP 40

typedef __bf16 bf16x8 __attribute__((ext_vector_type(8)));
typedef float f32x4 __attribute__((ext_vector_type(4)));

static __device__ __forceinline__ unsigned short f2bf(float f) {
  union { float f; unsigned int u; } v; v.f = f;
  unsigned int u = v.u;
  return (unsigned short)((u + 0x7FFF + ((u >> 16) & 1)) >> 16);  // RNE
}

// async global->LDS, 16B per lane; LDS dest = wave-uniform base + lane*16
static __device__ __forceinline__ void gload16(const unsigned short* gp, unsigned short* lp) {
  __builtin_amdgcn_global_load_lds(
      (const __attribute__((address_space(1))) unsigned int*)gp,
      (__attribute__((address_space(3))) unsigned int*)lp, 16, 0, 0);
}

__global__ void init_k(int* counts) {
  if (threadIdx.x < E_) counts[threadIdx.x] = 0;
}

// One wave per token: logits, softmax, top-2, counts; casts x row to bf16.
__global__ void router_k(const float* __restrict__ x, const float* __restrict__ gw,
                         unsigned short* __restrict__ xbf, float* __restrict__ topw,
                         int* __restrict__ topi, int* __restrict__ counts) {
  int wave = threadIdx.x >> 6, lane = threadIdx.x & 63;
  int n = blockIdx.x * 4 + wave;
  const float* xr = x + (size_t)n * D_;
  float v[16];
#pragma unroll
  for (int j = 0; j < 16; ++j) v[j] = xr[lane + 64 * j];
#pragma unroll
  for (int j = 0; j < 16; ++j) xbf[(size_t)n * D_ + lane + 64 * j] = f2bf(v[j]);
  float logit[E_];
  for (int e = 0; e < E_; ++e) {
    const float* g = gw + e * D_;
    float acc = 0.f;
#pragma unroll
    for (int j = 0; j < 16; ++j) acc += v[j] * g[lane + 64 * j];
#pragma unroll
    for (int off = 32; off > 0; off >>= 1) acc += __shfl_down(acc, off, 64);
    logit[e] = __shfl(acc, 0, 64);
  }
  if (lane == 0) {
    float m = logit[0];
    for (int e = 1; e < E_; ++e) m = fmaxf(m, logit[e]);
    float p[E_], s = 0.f;
    for (int e = 0; e < E_; ++e) { p[e] = expf(logit[e] - m); s += p[e]; }
    float inv = 1.f / s;
    for (int e = 0; e < E_; ++e) p[e] *= inv;
    int i0 = 0;
    for (int e = 1; e < E_; ++e) if (p[e] > p[i0]) i0 = e;
    int i1 = (i0 == 0) ? 1 : 0;
    for (int e = 0; e < E_; ++e) if (e != i0 && p[e] > p[i1]) i1 = e;
    topi[n * 2] = i0; topi[n * 2 + 1] = i1;
    topw[n * 2] = p[i0]; topw[n * 2 + 1] = p[i1];
    atomicAdd(&counts[i0], 1);
    atomicAdd(&counts[i1], 1);
  }
}

// prefix sum + (expert, mtile) table so every launched GEMM block has work
__global__ void scan_k(const int* __restrict__ counts, int* __restrict__ offs,
                       int* __restrict__ cursor, int* __restrict__ tile_e,
                       int* __restrict__ tile_m, int* __restrict__ ntiles) {
  if (threadIdx.x == 0) {
    int o = 0, idx = 0;
    for (int e = 0; e < E_; ++e) {
      offs[e] = o;
      int c = counts[e];
      int mt = (c + 127) >> 7;
      for (int m = 0; m < mt; ++m) {
        if (idx < TILE_CAP) { tile_e[idx] = e; tile_m[idx] = m; ++idx; }
      }
      o += c; cursor[e] = 0;
    }
    offs[E_] = o;
    ntiles[0] = idx;
  }
}

__global__ void fill_k(const int* __restrict__ topi, const int* __restrict__ offs,
                       int* __restrict__ cursor, int* __restrict__ rowlist,
                       int* __restrict__ slot_of) {
  int n = blockIdx.x * blockDim.x + threadIdx.x;
  if (n >= N_) return;
  for (int k = 0; k < K_; ++k) {
    int e = topi[n * 2 + k];
    int pos = offs[e] + atomicAdd(&cursor[e], 1);
    rowlist[pos] = n;
    slot_of[n * 2 + k] = pos;
  }
}

// fp32 [R,C] -> bf16 [C,R] (per batch z). Coalesced both sides.
__global__ void transpose_cvt_k(const float* __restrict__ in, unsigned short* __restrict__ out,
                                int R, int C) {
  __shared__ float tile[64][65];
  int cb = blockIdx.x * 64, rb = blockIdx.y * 64;
  const float* ip = in + (size_t)blockIdx.z * R * C;
  unsigned short* op = out + (size_t)blockIdx.z * R * C;
  int t = threadIdx.x;
  int cx = t & 63, ry = t >> 6;
#pragma unroll
  for (int i = 0; i < 16; ++i)
    tile[ry + i * 4][cx] = ip[(size_t)(rb + ry + i * 4) * C + cb + cx];
  __syncthreads();
  int wx = t & 31, wy = t >> 5;  // r-pair, c-group
#pragma unroll
  for (int i = 0; i < 8; ++i) {
    int cl = wy + i * 8;
    unsigned int u = (unsigned int)f2bf(tile[2 * wx][cl]) |
                     ((unsigned int)f2bf(tile[2 * wx + 1][cl]) << 16);
    ((unsigned int*)(op + (size_t)(cb + cl) * R + rb))[wx] = u;
  }
}

// Fused gate+up GEMM, 128(M)x64(N) tile, all-bf16, global_load_lds staging.
// A: gathered token rows [.,Kdim]; B: transposed weights [e][Ncols][Kdim].
// Epilogue: silu(g)*u -> bf16 Out[slot][Ncols].
__launch_bounds__(256, 3)
__global__ void gemm1_k(const unsigned short* __restrict__ Abase,
                        const int* __restrict__ rowlist,
                        const int* __restrict__ offs,
                        const int* __restrict__ tile_e, const int* __restrict__ tile_m,
                        const int* __restrict__ ntiles, int Mfixed,
                        const unsigned short* __restrict__ Bg_base,
                        const unsigned short* __restrict__ Bu_base,
                        int Ncols, int Kdim,
                        unsigned short* __restrict__ Out) {
  int e, mbase, Me, slotbase;
  if (tile_e) {
    if ((int)blockIdx.x >= ntiles[0]) return;
    e = tile_e[blockIdx.x]; mbase = tile_m[blockIdx.x] * 128;
    slotbase = offs[e]; Me = offs[e + 1] - slotbase;
  } else {
    e = 0; mbase = blockIdx.x * 128; slotbase = 0; Me = Mfixed;
  }
  int nbase = blockIdx.y * 64;
  const unsigned short* Bg = Bg_base + (size_t)e * Ncols * Kdim;
  const unsigned short* Bu = Bu_base + (size_t)e * Ncols * Kdim;

  __shared__ unsigned short As[128 * 32];
  __shared__ unsigned short Bgs[64 * 32];
  __shared__ unsigned short Bus[64 * 32];

  int t = threadIdx.x, lane = t & 63, wave = t >> 6;
  int wm = wave >> 1, wn = wave & 1;
  int chunk = lane & 3, rsub = lane >> 2;

  const unsigned short* aptr[2];
  unsigned int aoff[2];
#pragma unroll
  for (int i = 0; i < 2; ++i) {
    int r = wave * 32 + i * 16 + rsub;
    int grow = mbase + r;
    int src;
    if (rowlist) src = rowlist[slotbase + ((grow < Me) ? grow : 0)];
    else src = (grow < Me) ? grow : 0;
    aptr[i] = Abase + (size_t)src * Kdim + chunk * 8;
    aoff[i] = (unsigned)(wave * 32 + i * 16) * 32;
  }
  int bn = nbase + wave * 16 + rsub;
  const unsigned short* bgptr = Bg + (size_t)bn * Kdim + chunk * 8;
  const unsigned short* buptr = Bu + (size_t)bn * Kdim + chunk * 8;
  unsigned int boff = (unsigned)(wave * 16) * 32;

  f32x4 accg[4][2], accu[4][2];
#pragma unroll
  for (int i = 0; i < 4; ++i)
#pragma unroll
    for (int j = 0; j < 2; ++j) {
      accg[i][j] = f32x4{0.f, 0.f, 0.f, 0.f};
      accu[i][j] = f32x4{0.f, 0.f, 0.f, 0.f};
    }

  int nk = Kdim >> 5;
  for (int kt = 0; kt < nk; ++kt) {
    gload16(aptr[0] + kt * 32, &As[aoff[0]]);
    gload16(aptr[1] + kt * 32, &As[aoff[1]]);
    gload16(bgptr + kt * 32, &Bgs[boff]);
    gload16(buptr + kt * 32, &Bus[boff]);
    __syncthreads();
    bf16x8 afr[4];
#pragma unroll
    for (int i = 0; i < 4; ++i)
      afr[i] = *(const bf16x8*)&As[(wm * 64 + i * 16 + (lane & 15)) * 32 + (lane >> 4) * 8];
#pragma unroll
    for (int j = 0; j < 2; ++j) {
      bf16x8 bg = *(const bf16x8*)&Bgs[(wn * 32 + j * 16 + (lane & 15)) * 32 + (lane >> 4) * 8];
      bf16x8 bu = *(const bf16x8*)&Bus[(wn * 32 + j * 16 + (lane & 15)) * 32 + (lane >> 4) * 8];
#pragma unroll
      for (int i = 0; i < 4; ++i) {
        accg[i][j] = __builtin_amdgcn_mfma_f32_16x16x32_bf16(afr[i], bg, accg[i][j], 0, 0, 0);
        accu[i][j] = __builtin_amdgcn_mfma_f32_16x16x32_bf16(afr[i], bu, accu[i][j], 0, 0, 0);
      }
    }
    __syncthreads();
  }
  int r0 = (lane >> 4) * 4, cn = lane & 15;
#pragma unroll
  for (int i = 0; i < 4; ++i) {
#pragma unroll
    for (int rr = 0; rr < 4; ++rr) {
      int grow = mbase + wm * 64 + i * 16 + r0 + rr;
      if (grow < Me) {
        size_t rbase = (size_t)(slotbase + grow) * Ncols + nbase;
#pragma unroll
        for (int j = 0; j < 2; ++j) {
          float g = accg[i][j][rr], u = accu[i][j][rr];
          float a = (g / (1.f + __expf(-g))) * u;
          Out[rbase + wn * 32 + j * 16 + cn] = f2bf(a);
        }
      }
    }
  }
}

// Down GEMM, 128x128 tile, split-K via blockIdx.z, fp32 atomicAdd epilogue.
__launch_bounds__(256, 3)
__global__ void gemm2_k(const unsigned short* __restrict__ Abase,
                        const int* __restrict__ offs,
                        const int* __restrict__ tile_e, const int* __restrict__ tile_m,
                        const int* __restrict__ ntiles, int Mfixed,
                        const unsigned short* __restrict__ Bt_base,  // [e][Ncols][Kdim]
                        int Ncols, int Kdim, int kchunk,
                        float* __restrict__ Out) {
  int e, mbase, Me, slotbase;
  if (tile_e) {
    if ((int)blockIdx.x >= ntiles[0]) return;
    e = tile_e[blockIdx.x]; mbase = tile_m[blockIdx.x] * 128;
    slotbase = offs[e]; Me = offs[e + 1] - slotbase;
  } else {
    e = 0; mbase = blockIdx.x * 128; slotbase = 0; Me = Mfixed;
  }
  int nbase = blockIdx.y * 128;
  int koff = blockIdx.z * kchunk;
  const unsigned short* Bt = Bt_base + (size_t)e * Ncols * Kdim;

  __shared__ unsigned short As[128 * 32];
  __shared__ unsigned short Bs[128 * 32];

  int t = threadIdx.x, lane = t & 63, wave = t >> 6;
  int wm = wave >> 1, wn = wave & 1;
  int chunk = lane & 3, rsub = lane >> 2;

  const unsigned short* aptr[2];
  const unsigned short* bptr[2];
  unsigned int loff[2];
#pragma unroll
  for (int i = 0; i < 2; ++i) {
    int r = wave * 32 + i * 16 + rsub;
    int grow = mbase + r;
    int arow = slotbase + ((grow < Me) ? grow : 0);
    aptr[i] = Abase + (size_t)arow * Kdim + koff + chunk * 8;
    bptr[i] = Bt + (size_t)(nbase + r) * Kdim + koff + chunk * 8;
    loff[i] = (unsigned)(wave * 32 + i * 16) * 32;
  }

  f32x4 acc[4][4];
#pragma unroll
  for (int i = 0; i < 4; ++i)
#pragma unroll
    for (int j = 0; j < 4; ++j) acc[i][j] = f32x4{0.f, 0.f, 0.f, 0.f};

  int nk = kchunk >> 5;
  for (int kt = 0; kt < nk; ++kt) {
    gload16(aptr[0] + kt * 32, &As[loff[0]]);
    gload16(aptr[1] + kt * 32, &As[loff[1]]);
    gload16(bptr[0] + kt * 32, &Bs[loff[0]]);
    gload16(bptr[1] + kt * 32, &Bs[loff[1]]);
    __syncthreads();
    bf16x8 afr[4];
#pragma unroll
    for (int i = 0; i < 4; ++i)
      afr[i] = *(const bf16x8*)&As[(wm * 64 + i * 16 + (lane & 15)) * 32 + (lane >> 4) * 8];
#pragma unroll
    for (int j = 0; j < 4; ++j) {
      bf16x8 bb = *(const bf16x8*)&Bs[(wn * 64 + j * 16 + (lane & 15)) * 32 + (lane >> 4) * 8];
#pragma unroll
      for (int i = 0; i < 4; ++i)
        acc[i][j] = __builtin_amdgcn_mfma_f32_16x16x32_bf16(afr[i], bb, acc[i][j], 0, 0, 0);
    }
    __syncthreads();
  }
  int r0 = (lane >> 4) * 4, cn = lane & 15;
#pragma unroll
  for (int i = 0; i < 4; ++i) {
#pragma unroll
    for (int rr = 0; rr < 4; ++rr) {
      int grow = mbase + wm * 64 + i * 16 + r0 + rr;
      if (grow < Me) {
        size_t rbase = (size_t)(slotbase + grow) * Ncols + nbase;
#pragma unroll
        for (int j = 0; j < 4; ++j)
          atomicAdd(&Out[rbase + wn * 64 + j * 16 + cn], acc[i][j][rr]);
      }
    }
  }
}

// ---------------- fallback (Round-1) GEMMs, used only if ws too small ----------------
__launch_bounds__(256, 2)
__global__ void gemm1_old(const unsigned short* __restrict__ Abase,
                          const int* __restrict__ rowlist,
                          const int* __restrict__ offs, int Mfixed,
                          const float* __restrict__ Bg_base,
                          const float* __restrict__ Bu_base,
                          int Ncols, int Kdim,
                          unsigned short* __restrict__ Out) {
  int e = blockIdx.z;
  int Me, slotbase;
  if (offs) { slotbase = offs[e]; Me = offs[e + 1] - slotbase; }
  else      { slotbase = 0;       Me = Mfixed; }
  int mbase = blockIdx.x * 128;
  if (mbase >= Me) return;
  int nbase = blockIdx.y * 128;
  const float* Bg = Bg_base + (size_t)e * Kdim * Ncols;
  const float* Bu = Bu_base + (size_t)e * Kdim * Ncols;
  __shared__ unsigned short As[128][40];
  __shared__ unsigned short Bgs[128][40];
  __shared__ unsigned short Bus[128][40];
  int t = threadIdx.x, lane = t & 63, wave = t >> 6;
  int wm = wave >> 1, wn = wave & 1;
  f32x4 accg[4][4], accu[4][4];
#pragma unroll
  for (int i = 0; i < 4; ++i)
#pragma unroll
    for (int j = 0; j < 4; ++j) {
      accg[i][j] = f32x4{0.f, 0.f, 0.f, 0.f};
      accu[i][j] = f32x4{0.f, 0.f, 0.f, 0.f};
    }
  int ar = t >> 1, akh = t & 1;
  int arow = mbase + ar;
  int asrc = 0;
  if (arow < Me) asrc = rowlist ? rowlist[slotbase + arow] : arow;
  const unsigned short* aptr = Abase + (size_t)asrc * Kdim + akh * 16;
  int bfc = t & 127, bkh = t >> 7;
  const float* bgp = Bg + (size_t)(bkh * 16) * Ncols + nbase + bfc;
  const float* bup = Bu + (size_t)(bkh * 16) * Ncols + nbase + bfc;
  int nk = Kdim >> 5;
  for (int kt = 0; kt < nk; ++kt) {
    uint4 a0 = *(const uint4*)(aptr + kt * 32);
    uint4 a1 = *(const uint4*)(aptr + kt * 32 + 8);
    *(uint4*)&As[ar][akh * 16] = a0;
    *(uint4*)&As[ar][akh * 16 + 8] = a1;
    {
      const float* p0 = bgp + (size_t)kt * 32 * Ncols;
      float bv[16]; unsigned short h[16];
#pragma unroll
      for (int i = 0; i < 16; ++i) bv[i] = p0[(size_t)i * Ncols];
#pragma unroll
      for (int i = 0; i < 16; ++i) h[i] = f2bf(bv[i]);
      *(uint4*)&Bgs[bfc][bkh * 16] = *(uint4*)&h[0];
      *(uint4*)&Bgs[bfc][bkh * 16 + 8] = *(uint4*)&h[8];
    }
    {
      const float* p1 = bup + (size_t)kt * 32 * Ncols;
      float bv[16]; unsigned short h[16];
#pragma unroll
      for (int i = 0; i < 16; ++i) bv[i] = p1[(size_t)i * Ncols];
#pragma unroll
      for (int i = 0; i < 16; ++i) h[i] = f2bf(bv[i]);
      *(uint4*)&Bus[bfc][bkh * 16] = *(uint4*)&h[0];
      *(uint4*)&Bus[bfc][bkh * 16 + 8] = *(uint4*)&h[8];
    }
    __syncthreads();
    bf16x8 afr[4];
#pragma unroll
    for (int i = 0; i < 4; ++i)
      afr[i] = *(const bf16x8*)&As[wm * 64 + i * 16 + (lane & 15)][(lane >> 4) * 8];
#pragma unroll
    for (int j = 0; j < 4; ++j) {
      bf16x8 bg = *(const bf16x8*)&Bgs[wn * 64 + j * 16 + (lane & 15)][(lane >> 4) * 8];
      bf16x8 bu = *(const bf16x8*)&Bus[wn * 64 + j * 16 + (lane & 15)][(lane >> 4) * 8];
#pragma unroll
      for (int i = 0; i < 4; ++i) {
        accg[i][j] = __builtin_amdgcn_mfma_f32_16x16x32_bf16(afr[i], bg, accg[i][j], 0, 0, 0);
        accu[i][j] = __builtin_amdgcn_mfma_f32_16x16x32_bf16(afr[i], bu, accu[i][j], 0, 0, 0);
      }
    }
    __syncthreads();
  }
  int r0 = (lane >> 4) * 4, cn = lane & 15;
#pragma unroll
  for (int i = 0; i < 4; ++i) {
#pragma unroll
    for (int rr = 0; rr < 4; ++rr) {
      int grow = mbase + wm * 64 + i * 16 + r0 + rr;
      if (grow < Me) {
        size_t rbase = (size_t)(slotbase + grow) * Ncols + nbase;
#pragma unroll
        for (int j = 0; j < 4; ++j) {
          float g = accg[i][j][rr], u = accu[i][j][rr];
          float a = (g / (1.f + __expf(-g))) * u;
          Out[rbase + wn * 64 + j * 16 + cn] = f2bf(a);
        }
      }
    }
  }
}

__launch_bounds__(256, 2)
__global__ void gemm2_old(const unsigned short* __restrict__ Abase,
                          const int* __restrict__ offs, int Mfixed,
                          const float* __restrict__ B_base,
                          int Ncols, int Kdim,
                          float* __restrict__ Out) {
  int e = blockIdx.z;
  int Me, slotbase;
  if (offs) { slotbase = offs[e]; Me = offs[e + 1] - slotbase; }
  else      { slotbase = 0;       Me = Mfixed; }
  int mbase = blockIdx.x * 128;
  if (mbase >= Me) return;
  int nbase = blockIdx.y * 128;
  const float* B = B_base + (size_t)e * Kdim * Ncols;
  __shared__ unsigned short As[128][40];
  __shared__ unsigned short Bs[128][40];
  int t = threadIdx.x, lane = t & 63, wave = t >> 6;
  int wm = wave >> 1, wn = wave & 1;
  f32x4 acc[4][4];
#pragma unroll
  for (int i = 0; i < 4; ++i)
#pragma unroll
    for (int j = 0; j < 4; ++j) acc[i][j] = f32x4{0.f, 0.f, 0.f, 0.f};
  int ar = t >> 1, akh = t & 1;
  int arow = slotbase + ((mbase + ar < Me) ? (mbase + ar) : 0);
  const unsigned short* aptr = Abase + (size_t)arow * Kdim + akh * 16;
  int bfc = t & 127, bkh = t >> 7;
  const float* bp = B + (size_t)(bkh * 16) * Ncols + nbase + bfc;
  int nk = Kdim >> 5;
  for (int kt = 0; kt < nk; ++kt) {
    uint4 a0 = *(const uint4*)(aptr + kt * 32);
    uint4 a1 = *(const uint4*)(aptr + kt * 32 + 8);
    *(uint4*)&As[ar][akh * 16] = a0;
    *(uint4*)&As[ar][akh * 16 + 8] = a1;
    {
      const float* p0 = bp + (size_t)kt * 32 * Ncols;
      float bv[16]; unsigned short h[16];
#pragma unroll
      for (int i = 0; i < 16; ++i) bv[i] = p0[(size_t)i * Ncols];
#pragma unroll
      for (int i = 0; i < 16; ++i) h[i] = f2bf(bv[i]);
      *(uint4*)&Bs[bfc][bkh * 16] = *(uint4*)&h[0];
      *(uint4*)&Bs[bfc][bkh * 16 + 8] = *(uint4*)&h[8];
    }
    __syncthreads();
    bf16x8 afr[4];
#pragma unroll
    for (int i = 0; i < 4; ++i)
      afr[i] = *(const bf16x8*)&As[wm * 64 + i * 16 + (lane & 15)][(lane >> 4) * 8];
#pragma unroll
    for (int j = 0; j < 4; ++j) {
      bf16x8 bb = *(const bf16x8*)&Bs[wn * 64 + j * 16 + (lane & 15)][(lane >> 4) * 8];
#pragma unroll
      for (int i = 0; i < 4; ++i)
        acc[i][j] = __builtin_amdgcn_mfma_f32_16x16x32_bf16(afr[i], bb, acc[i][j], 0, 0, 0);
    }
    __syncthreads();
  }
  int r0 = (lane >> 4) * 4, cn = lane & 15;
#pragma unroll
  for (int i = 0; i < 4; ++i) {
#pragma unroll
    for (int rr = 0; rr < 4; ++rr) {
      int grow = mbase + wm * 64 + i * 16 + r0 + rr;
      if (grow < Me) {
        size_t rbase = (size_t)(slotbase + grow) * Ncols + nbase;
#pragma unroll
        for (int j = 0; j < 4; ++j)
          Out[rbase + wn * 64 + j * 16 + cn] = acc[i][j][rr];
      }
    }
  }
}

__global__ void combine_k(const float* __restrict__ eo, const float* __restrict__ sh,
                          const float* __restrict__ topw, const int* __restrict__ slot_of,
                          float* __restrict__ out) {
  int idx = blockIdx.x * blockDim.x + threadIdx.x;
  int n = idx >> 8;
  int d4 = idx & 255;
  float w0 = topw[n * 2], w1 = topw[n * 2 + 1];
  int s0 = slot_of[n * 2], s1 = slot_of[n * 2 + 1];
  float4 a = ((const float4*)(eo + (size_t)s0 * D_))[d4];
  float4 b = ((const float4*)(eo + (size_t)s1 * D_))[d4];
  float4 c = ((const float4*)(sh + (size_t)n * D_))[d4];
  float4 r;
  r.x = w0 * a.x + w1 * b.x + c.x;
  r.y = w0 * a.y + w1 * b.y + c.y;
  r.z = w0 * a.z + w1 * b.z + c.z;
  r.w = w0 * a.w + w1 * b.w + c.w;
  ((float4*)out)[idx] = r;
}

extern "C" void kernel_launch(void* const* d_in, const int* in_sizes, int n_in,
                              void* d_out, int out_size, void* d_ws, size_t ws_size,
                              hipStream_t stream) {
  const float* x  = (const float*)d_in[0];
  const float* gw = (const float*)d_in[1];
  const float* gk = (const float*)d_in[2];
  const float* uk = (const float*)d_in[3];
  const float* dk = (const float*)d_in[4];
  const float* sg = (const float*)d_in[5];
  const float* su = (const float*)d_in[6];
  const float* sd = (const float*)d_in[7];
  float* out = (float*)d_out;

  char* w = (char*)d_ws;
  size_t o = 0;
  auto take = [&](size_t bytes) -> void* {
    void* p = w + o;
    o += (bytes + 255) & ~(size_t)255;
    return p;
  };
  // common buffers (fit in the Round-1 footprint)
  unsigned short* xbf    = (unsigned short*)take((size_t)N_ * D_ * 2);
  unsigned short* act    = (unsigned short*)take((size_t)ROWS_CAP * F_ * 2);
  unsigned short* act_sh = (unsigned short*)take((size_t)N_ * FS_ * 2);
  float* eo     = (float*)take((size_t)ROWS_CAP * D_ * 4);
  float* sh_out = (float*)take((size_t)N_ * D_ * 4);
  float* topw   = (float*)take((size_t)N_ * 2 * 4);
  int* topi     = (int*)take((size_t)N_ * 2 * 4);
  int* slot_of  = (int*)take((size_t)N_ * 2 * 4);
  int* rowlist  = (int*)take((size_t)ROWS_CAP * 4);
  int* counts   = (int*)take(E_ * 4);
  int* offs     = (int*)take((E_ + 1) * 4);
  int* cursor   = (int*)take(E_ * 4);
  int* tile_e   = (int*)take(TILE_CAP * 4);
  int* tile_m   = (int*)take(TILE_CAP * 4);
  int* ntiles   = (int*)take(4);
  // full-path: bf16 transposed weights
  unsigned short* gkt = (unsigned short*)take((size_t)E_ * D_ * F_ * 2);
  unsigned short* ukt = (unsigned short*)take((size_t)E_ * D_ * F_ * 2);
  unsigned short* dkt = (unsigned short*)take((size_t)E_ * D_ * F_ * 2);
  unsigned short* sgt = (unsigned short*)take((size_t)D_ * FS_ * 2);
  unsigned short* sut = (unsigned short*)take((size_t)D_ * FS_ * 2);
  unsigned short* sdt = (unsigned short*)take((size_t)D_ * FS_ * 2);
  bool full = (ws_size >= o);

  hipLaunchKernelGGL(init_k, dim3(1), dim3(64), 0, stream, counts);
  hipLaunchKernelGGL(router_k, dim3(N_ / 4), dim3(256), 0, stream,
                     x, gw, xbf, topw, topi, counts);
  hipLaunchKernelGGL(scan_k, dim3(1), dim3(32), 0, stream,
                     counts, offs, cursor, tile_e, tile_m, ntiles);
  hipLaunchKernelGGL(fill_k, dim3(N_ / 256), dim3(256), 0, stream,
                     topi, offs, cursor, rowlist, slot_of);

  if (full) {
    // weight transpose+convert: fp32 [R,C] -> bf16 [C,R]
    hipLaunchKernelGGL(transpose_cvt_k, dim3(F_ / 64, D_ / 64, E_), dim3(256), 0, stream,
                       gk, gkt, D_, F_);
    hipLaunchKernelGGL(transpose_cvt_k, dim3(F_ / 64, D_ / 64, E_), dim3(256), 0, stream,
                       uk, ukt, D_, F_);
    hipLaunchKernelGGL(transpose_cvt_k, dim3(D_ / 64, F_ / 64, E_), dim3(256), 0, stream,
                       dk, dkt, F_, D_);
    hipLaunchKernelGGL(transpose_cvt_k, dim3(FS_ / 64, D_ / 64, 1), dim3(256), 0, stream,
                       sg, sgt, D_, FS_);
    hipLaunchKernelGGL(transpose_cvt_k, dim3(FS_ / 64, D_ / 64, 1), dim3(256), 0, stream,
                       su, sut, D_, FS_);
    hipLaunchKernelGGL(transpose_cvt_k, dim3(D_ / 64, FS_ / 64, 1), dim3(256), 0, stream,
                       sd, sdt, FS_, D_);
    // zero split-K accumulators
    hipMemsetAsync(eo, 0, (size_t)ROWS_CAP * D_ * 4, stream);
    hipMemsetAsync(sh_out, 0, (size_t)N_ * D_ * 4, stream);
    // routed gate/up
    hipLaunchKernelGGL(gemm1_k, dim3(TILE_CAP, F_ / 64), dim3(256), 0, stream,
                       xbf, rowlist, offs, tile_e, tile_m, ntiles, 0,
                       gkt, ukt, F_, D_, act);
    // shared gate/up
    hipLaunchKernelGGL(gemm1_k, dim3(N_ / 128, FS_ / 64), dim3(256), 0, stream,
                       xbf, (const int*)nullptr, (const int*)nullptr,
                       (const int*)nullptr, (const int*)nullptr, (const int*)nullptr, N_,
                       sgt, sut, FS_, D_, act_sh);
    // routed down (split-K = 2)
    hipLaunchKernelGGL(gemm2_k, dim3(TILE_CAP, D_ / 128, 2), dim3(256), 0, stream,
                       act, offs, tile_e, tile_m, ntiles, 0,
                       dkt, D_, F_, F_ / 2, eo);
    // shared down (split-K = 2)
    hipLaunchKernelGGL(gemm2_k, dim3(N_ / 128, D_ / 128, 2), dim3(256), 0, stream,
                       act_sh, (const int*)nullptr, (const int*)nullptr,
                       (const int*)nullptr, (const int*)nullptr, N_,
                       sdt, D_, FS_, FS_ / 2, sh_out);
  } else {
    hipLaunchKernelGGL(gemm1_old, dim3(16, F_ / 128, E_), dim3(256), 0, stream,
                       xbf, rowlist, offs, 0, gk, uk, F_, D_, act);
    hipLaunchKernelGGL(gemm1_old, dim3(16, FS_ / 128, 1), dim3(256), 0, stream,
                       xbf, (const int*)nullptr, (const int*)nullptr, N_, sg, su, FS_, D_, act_sh);
    hipLaunchKernelGGL(gemm2_old, dim3(16, D_ / 128, E_), dim3(256), 0, stream,
                       act, offs, 0, dk, D_, F_, eo);
    hipLaunchKernelGGL(gemm2_old, dim3(16, D_ / 128, 1), dim3(256), 0, stream,
                       act_sh, (const int*)nullptr, N_, sd, D_, FS_, sh_out);
  }
  hipLaunchKernelGGL(combine_k, dim3((N_ * D_ / 4) / 256), dim3(256), 0, stream,
                     eo, sh_out, topw, slot_of, out);
}